// Round 7
// baseline (398.083 us; speedup 1.0000x reference)
//
#include <hip/hip_runtime.h>
#include <hip/hip_bf16.h>

// ---------------------------------------------------------------------------
// Gemma-style attention block, MI355X (gfx950).
// B=1, T=4096, D=2048, N=16 q-heads, KH=8 kv-heads (GQA G=2), H=128,
// sliding window 1024, causal, RMSNorm(q,k) + RoPE, attn scale folded into q.
//
// Pipeline:
//  k_cvt_x      : x fp32 -> xb bf16 [T][D]
//  k_tr_cvt_f32 : weights fp32 -> bf16, transposed to K-contiguous (B^T) form
//                 WqkvT [4096][2048] (rows: 2048 q | 1024 k | 1024 v), WoT [2048][2048]
//  k_rope_table : cos/sin table [T][64]
//  k_gemm_bt    : xb @ WqkvT^T -> Cqkv bf16 [T][4096]   (m97-style MFMA GEMM)
//  k_normrope   : RMSNorm+RoPE; q -> qro [16][T][128] (*ATTN_SCALE),
//                 k -> ksw [8][T][128] pre-XOR-swizzled (16B chunks) for LDS staging
//  k_tr_v       : V -> vt [8][128][T] (transposed for PV B-fragments)
//  k_attn       : flash attention (KV tile 64) -> enc bf16 [T][2048]
//  k_gemm_bt    : enc @ WoT^T -> d_out fp32
// ---------------------------------------------------------------------------

#define DEVINL __device__ __forceinline__

typedef __attribute__((ext_vector_type(4))) float f32x4;
typedef __attribute__((ext_vector_type(8))) short s16x8;
typedef __attribute__((ext_vector_type(4))) unsigned int u32x4;

constexpr int T = 4096, D = 2048, NQ = 16, KH = 8, H = 128;
constexpr int NCOLS = 4096;              // q(2048) | k(1024) | v(1024)
constexpr float EPS = 1e-6f;
constexpr float ATTN_SCALE = 0.08838834764831845f;
constexpr int WINDOW = 1024;

DEVINL unsigned short f2bf(float f) {
    union { float f; unsigned int u; } v; v.f = f;
    unsigned int u = v.u;
    return (unsigned short)((u + 0x7fffu + ((u >> 16) & 1u)) >> 16);
}
DEVINL float bf2f(unsigned short h) {
    union { unsigned int u; float f; } v; v.u = ((unsigned int)h) << 16;
    return v.f;
}
DEVINL void gload_lds16(const unsigned short* g, unsigned short* l) {
    __builtin_amdgcn_global_load_lds(
        (const __attribute__((address_space(1))) unsigned int*)g,
        (__attribute__((address_space(3))) unsigned int*)l, 16, 0, 0);
}

// ---------------------------------------------------------------- convert x
__global__ __launch_bounds__(256) void k_cvt_x(const float* __restrict__ x,
                                               unsigned short* __restrict__ xb, int n8) {
    int i = blockIdx.x * 256 + threadIdx.x;
    if (i >= n8) return;
    const float4* src = (const float4*)x + (long)i * 2;
    float4 a = src[0], b = src[1];
    s16x8 o;
    o[0] = (short)f2bf(a.x); o[1] = (short)f2bf(a.y);
    o[2] = (short)f2bf(a.z); o[3] = (short)f2bf(a.w);
    o[4] = (short)f2bf(b.x); o[5] = (short)f2bf(b.y);
    o[6] = (short)f2bf(b.z); o[7] = (short)f2bf(b.w);
    ((s16x8*)xb)[i] = o;
}

// ---------------------------------------------- transpose+convert f32 slabs
// src [R][C] fp32 per slab -> dst [C][R] bf16 per slab
__global__ __launch_bounds__(256) void k_tr_cvt_f32(const float* __restrict__ src,
                                                    unsigned short* __restrict__ dst,
                                                    int R, int C, long srcSlab, long dstSlab) {
    __shared__ float tile[32][33];
    int slab = blockIdx.z;
    src += (long)slab * srcSlab; dst += (long)slab * dstSlab;
    int c0 = blockIdx.x * 32, r0 = blockIdx.y * 32;
    int tx = threadIdx.x, ty = threadIdx.y;     // (32, 8)
    #pragma unroll
    for (int i = 0; i < 32; i += 8)
        tile[ty + i][tx] = src[(long)(r0 + ty + i) * C + c0 + tx];
    __syncthreads();
    #pragma unroll
    for (int i = 0; i < 32; i += 8)
        dst[(long)(c0 + ty + i) * R + r0 + tx] = f2bf(tile[tx][ty + i]);
}

// ------------------------------------------------------------- rope table
__global__ __launch_bounds__(256) void k_rope_table(float2* __restrict__ rt) {
    int idx = blockIdx.x * 256 + threadIdx.x;     // t*64 + j
    int t = idx >> 6, j = idx & 63;
    float inv = expf(-(float)j * (logf(10000.0f) / 64.0f));   // 10000^(-j/64)
    float a = (float)t * inv;
    float s, c;
    sincosf(a, &s, &c);
    rt[idx] = make_float2(c, s);
}

// ---------------------------------------------------------------- bf16 GEMM
// C[M][N] = A[M][K] * Bt[N][K]^T, 128x128 tile, BK=64, 4 waves, XOR-swizzled
// LDS via pre-swizzled per-lane global source, global_load_lds width 16.
template <bool BF16OUT>
__global__ __launch_bounds__(256) void k_gemm_bt(const unsigned short* __restrict__ A,
                                                 const unsigned short* __restrict__ Bt,
                                                 void* __restrict__ Cout,
                                                 int M, int N, int K) {
    constexpr int BK = 64;
    __shared__ __align__(16) unsigned short As[128 * BK];
    __shared__ __align__(16) unsigned short Bs[128 * BK];

    int nwg = gridDim.x, bid = blockIdx.x;
    int cpx = nwg >> 3;
    int wg = (bid & 7) * cpx + (bid >> 3);        // XCD swizzle (nwg % 8 == 0)
    int nbn = N >> 7;
    int bm = wg / nbn, bn = wg % nbn;

    int tid = threadIdx.x;
    int w = tid >> 6, l = tid & 63;
    int g = l >> 4, lr = l & 15;
    int wrow = (w >> 1) * 64, wcol = (w & 1) * 64;

    const unsigned short* Abase = A + (long)(bm * 128) * K;
    const unsigned short* Bbase = Bt + (long)(bn * 128) * K;

    f32x4 acc[4][4] = {};

    for (int k0 = 0; k0 < K; k0 += BK) {
        #pragma unroll
        for (int j = 0; j < 4; ++j) {
            int chunk = j * 256 + tid;
            int row = chunk >> 3, slot = chunk & 7;
            int sl = slot ^ (row & 7);            // pre-swizzle the source
            gload_lds16(Abase + (long)row * K + k0 + sl * 8,
                        As + (j * 256 + w * 64) * 8);
        }
        #pragma unroll
        for (int j = 0; j < 4; ++j) {
            int chunk = j * 256 + tid;
            int row = chunk >> 3, slot = chunk & 7;
            int sl = slot ^ (row & 7);
            gload_lds16(Bbase + (long)row * K + k0 + sl * 8,
                        Bs + (j * 256 + w * 64) * 8);
        }
        __syncthreads();
        #pragma unroll
        for (int kk = 0; kk < 2; ++kk) {
            s16x8 af[4], bf[4];
            #pragma unroll
            for (int mi = 0; mi < 4; ++mi) {
                int row = wrow + mi * 16 + lr;
                int slot = (kk * 4 + g) ^ (row & 7);
                af[mi] = *(const s16x8*)(As + row * BK + slot * 8);
            }
            #pragma unroll
            for (int ni = 0; ni < 4; ++ni) {
                int row = wcol + ni * 16 + lr;
                int slot = (kk * 4 + g) ^ (row & 7);
                bf[ni] = *(const s16x8*)(Bs + row * BK + slot * 8);
            }
            #pragma unroll
            for (int mi = 0; mi < 4; ++mi)
                #pragma unroll
                for (int ni = 0; ni < 4; ++ni)
                    acc[mi][ni] = __builtin_amdgcn_mfma_f32_16x16x32_bf16(
                        af[mi], bf[ni], acc[mi][ni], 0, 0, 0);
        }
        __syncthreads();
    }

    int crow0 = bm * 128 + wrow + g * 4;
    int ccol0 = bn * 128 + wcol + lr;
    #pragma unroll
    for (int mi = 0; mi < 4; ++mi)
        #pragma unroll
        for (int ni = 0; ni < 4; ++ni)
            #pragma unroll
            for (int j = 0; j < 4; ++j) {
                long r = crow0 + mi * 16 + j;
                long c = ccol0 + ni * 16;
                if (BF16OUT)
                    ((unsigned short*)Cout)[r * N + c] = f2bf(acc[mi][ni][j]);
                else
                    ((float*)Cout)[r * N + c] = acc[mi][ni][j];
            }
}

// --------------------------------------------------------- RMSNorm + RoPE
// One wave per (head, t) row: lane l handles (h=l, h=l+64) rope pair.
__global__ __launch_bounds__(256) void k_normrope(const unsigned short* __restrict__ Cqkv,
                                                  const float* __restrict__ qscale,
                                                  const float* __restrict__ kscale,
                                                  const float2* __restrict__ rt,
                                                  unsigned short* __restrict__ qro,
                                                  unsigned short* __restrict__ ksw) {
    int w = threadIdx.x >> 6, l = threadIdx.x & 63;
    int rid = blockIdx.x * 4 + w;                 // [0, 24*4096)
    int head = rid >> 12;                         // 0..23 (16 q + 8 k)
    int t = rid & 4095;
    int col0 = (head < NQ) ? head * H : D + (head - NQ) * H;
    const unsigned short* row = Cqkv + (long)t * NCOLS + col0;
    float x1 = bf2f(row[l]), x2 = bf2f(row[l + 64]);
    float ss = x1 * x1 + x2 * x2;
    #pragma unroll
    for (int off = 1; off < 64; off <<= 1) ss += __shfl_xor(ss, off);
    float r = rsqrtf(ss * (1.0f / 128.0f) + EPS);
    const float* scale = (head < NQ) ? qscale : kscale;
    float y1 = x1 * r * scale[l], y2 = x2 * r * scale[l + 64];
    float2 cs = rt[t * 64 + l];
    float o1 = y1 * cs.x - y2 * cs.y;
    float o2 = y2 * cs.x + y1 * cs.y;
    if (head < NQ) {
        o1 *= ATTN_SCALE; o2 *= ATTN_SCALE;
        unsigned short* dst = qro + ((long)head * T + t) * H;
        dst[l] = f2bf(o1); dst[l + 64] = f2bf(o2);
    } else {
        unsigned short* dst = ksw + ((long)(head - NQ) * T + t) * H;
        int sx = (t & 7) << 3;                    // 16B-chunk XOR pre-swizzle
        dst[l ^ sx] = f2bf(o1); dst[(l + 64) ^ sx] = f2bf(o2);
    }
}

// --------------------------------------------------- transpose V -> [kh][h][s]
__global__ __launch_bounds__(256) void k_tr_v(const unsigned short* __restrict__ Cqkv,
                                              unsigned short* __restrict__ vt) {
    __shared__ unsigned short tile[32][33];
    int kh = blockIdx.z;
    int h0 = blockIdx.y * 32;
    int s0 = blockIdx.x * 32;
    int tx = threadIdx.x, ty = threadIdx.y;
    #pragma unroll
    for (int i = 0; i < 32; i += 8)
        tile[ty + i][tx] = Cqkv[(long)(s0 + ty + i) * NCOLS + 3072 + kh * H + h0 + tx];
    __syncthreads();
    #pragma unroll
    for (int i = 0; i < 32; i += 8)
        vt[((long)kh * H + h0 + ty + i) * T + s0 + tx] = tile[tx][ty + i];
}

// ------------------------------------------------------------- attention
// Block: 4 waves x 16 q-rows (64 q-rows), one head. KV tile = 64 keys.
__global__ __launch_bounds__(256) void k_attn(const unsigned short* __restrict__ qro,
                                              const unsigned short* __restrict__ ksw,
                                              const unsigned short* __restrict__ vt,
                                              unsigned short* __restrict__ enc) {
    __shared__ __align__(16) unsigned short Ks[64 * 128];      // XOR-swizzled chunks
    __shared__ __align__(16) unsigned short Vs[128 * 72];      // [h][s], padded rows
    __shared__ __align__(16) unsigned short Ps[4][16 * 72];    // per-wave P

    int nwg = gridDim.x, bid = blockIdx.x;
    int cpx = nwg >> 3;
    int wg = (bid & 7) * cpx + (bid >> 3);
    int n = wg >> 6;                 // head
    int qblk = wg & 63;
    int kvh = n >> 1;                // GQA: k = n // 2
    int q0 = qblk * 64;

    int tid = threadIdx.x, w = tid >> 6, l = tid & 63;
    int g = l >> 4, lr = l & 15;
    int qw0 = q0 + w * 16;

    const unsigned short* Kb = ksw + (long)kvh * T * H;
    const unsigned short* Vb = vt + (long)kvh * H * T;

    // Q fragments (A-operand), attn-scale already folded in
    s16x8 qf[4];
    const unsigned short* qrow = qro + ((long)n * T + qw0 + lr) * H;
    #pragma unroll
    for (int c = 0; c < 4; ++c)
        qf[c] = *(const s16x8*)(qrow + c * 32 + g * 8);

    float m[4] = {-1e30f, -1e30f, -1e30f, -1e30f};
    float sden[4] = {};
    f32x4 acc[8] = {};

    int ts_lo = q0 - (WINDOW - 1);
    ts_lo = ts_lo < 0 ? 0 : (ts_lo & ~63);

    for (int ts = ts_lo; ts <= q0; ts += 64) {
        // stage K tile (linear copy; source is pre-swizzled)
        #pragma unroll
        for (int j = 0; j < 4; ++j)
            gload_lds16(Kb + (long)ts * H + (j * 256 + tid) * 8,
                        Ks + (j * 256 + w * 64) * 8);
        // stage V tile (reg-staged into padded LDS rows)
        u32x4 vreg[4];
        #pragma unroll
        for (int j = 0; j < 4; ++j) {
            int chunk = j * 256 + tid;
            int h = chunk >> 3, slot = chunk & 7;
            vreg[j] = *(const u32x4*)(Vb + (long)h * T + ts + slot * 8);
        }
        #pragma unroll
        for (int j = 0; j < 4; ++j) {
            int chunk = j * 256 + tid;
            int h = chunk >> 3, slot = chunk & 7;
            *(u32x4*)(Vs + h * 72 + slot * 8) = vreg[j];
        }
        __syncthreads();

        bool active = !(ts > qw0 + 15 || ts + 63 < qw0 - (WINDOW - 1));
        if (active) {
            // S = Q K^T : 4 s-subtiles of 16
            f32x4 sf[4];
            #pragma unroll
            for (int sh = 0; sh < 4; ++sh) {
                f32x4 s4 = {};
                int srow = sh * 16 + lr;
                int sx = srow & 7;
                #pragma unroll
                for (int c = 0; c < 4; ++c) {
                    int slot = (c * 4 + g) ^ sx;
                    s16x8 kf = *(const s16x8*)(Ks + srow * 128 + slot * 8);
                    s4 = __builtin_amdgcn_mfma_f32_16x16x32_bf16(qf[c], kf, s4, 0, 0, 0);
                }
                sf[sh] = s4;
            }
            // mask + online softmax (rows g*4+j, cols = 16-lane groups)
            float scalef[4];
            #pragma unroll
            for (int j = 0; j < 4; ++j) {
                int q = qw0 + g * 4 + j;
                float mx = -1e30f;
                #pragma unroll
                for (int sh = 0; sh < 4; ++sh) {
                    int s = ts + sh * 16 + lr;
                    bool valid = (s <= q) && (q - s < WINDOW);
                    sf[sh][j] = valid ? sf[sh][j] : -1e30f;
                    mx = fmaxf(mx, sf[sh][j]);
                }
                mx = fmaxf(mx, __shfl_xor(mx, 1));
                mx = fmaxf(mx, __shfl_xor(mx, 2));
                mx = fmaxf(mx, __shfl_xor(mx, 4));
                mx = fmaxf(mx, __shfl_xor(mx, 8));
                float mnew = fmaxf(m[j], mx);
                scalef[j] = __expf(m[j] - mnew);
                float ps = 0.f;
                #pragma unroll
                for (int sh = 0; sh < 4; ++sh) {
                    float p = (sf[sh][j] > -1e29f) ? __expf(sf[sh][j] - mnew) : 0.f;
                    sf[sh][j] = p;
                    ps += p;
                }
                ps += __shfl_xor(ps, 1);
                ps += __shfl_xor(ps, 2);
                ps += __shfl_xor(ps, 4);
                ps += __shfl_xor(ps, 8);
                sden[j] = sden[j] * scalef[j] + ps;
                m[j] = mnew;
            }
            #pragma unroll
            for (int hc = 0; hc < 8; ++hc)
                #pragma unroll
                for (int j = 0; j < 4; ++j)
                    acc[hc][j] *= scalef[j];
            // P -> LDS (bf16), per-wave buffer
            unsigned short* P = &Ps[w][0];
            #pragma unroll
            for (int j = 0; j < 4; ++j) {
                int prow = g * 4 + j;
                #pragma unroll
                for (int sh = 0; sh < 4; ++sh)
                    P[prow * 72 + sh * 16 + lr] = f2bf(sf[sh][j]);
            }
            // PV: acc[q][h] += P[q][s] * V[s][h]
            #pragma unroll
            for (int kk = 0; kk < 2; ++kk) {
                s16x8 pf = *(const s16x8*)(P + lr * 72 + kk * 32 + g * 8);
                #pragma unroll
                for (int hc = 0; hc < 8; ++hc) {
                    int h = hc * 16 + lr;
                    s16x8 vf = *(const s16x8*)(Vs + h * 72 + kk * 32 + g * 8);
                    acc[hc] = __builtin_amdgcn_mfma_f32_16x16x32_bf16(pf, vf, acc[hc], 0, 0, 0);
                }
            }
        }
        __syncthreads();
    }

    // epilogue: normalize and write enc[t][n*128+h]
    #pragma unroll
    for (int j = 0; j < 4; ++j) {
        float inv = 1.0f / sden[j];
        long r = qw0 + g * 4 + j;
        unsigned short* dst = enc + r * (long)D + n * H;
        #pragma unroll
        for (int hc = 0; hc < 8; ++hc)
            dst[hc * 16 + lr] = f2bf(acc[hc][j] * inv);
    }
}

// ---------------------------------------------------------------------------
extern "C" void kernel_launch(void* const* d_in, const int* in_sizes, int n_in,
                              void* d_out, int out_size, void* d_ws, size_t ws_size,
                              hipStream_t stream) {
    const float* x   = (const float*)d_in[0];
    const float* qk  = (const float*)d_in[1];
    const float* kvk = (const float*)d_in[2];
    const float* ok  = (const float*)d_in[3];
    const float* qs  = (const float*)d_in[4];
    const float* ks  = (const float*)d_in[5];

    char* ws = (char*)d_ws;
    unsigned short* xb    = (unsigned short*)(ws);                 // 16 MB
    unsigned short* WqkvT = (unsigned short*)(ws + 16777216);      // 16 MB
    unsigned short* WoT   = (unsigned short*)(ws + 33554432);      //  8 MB
    unsigned short* Cqkv  = (unsigned short*)(ws + 41943040);      // 32 MB
    unsigned short* qro   = (unsigned short*)(ws + 75497472);      // 16 MB
    unsigned short* kswp  = (unsigned short*)(ws + 92274688);      //  8 MB
    unsigned short* vt    = (unsigned short*)(ws + 100663296);     //  8 MB
    unsigned short* enc   = (unsigned short*)(ws + 109051904);     // 16 MB
    float2*         rt    = (float2*)(ws + 125829120);             //  2 MB

    dim3 tb(32, 8);
    k_cvt_x<<<4096, 256, 0, stream>>>(x, xb, T * D / 8);
    // q_kernel [16][2048][128] -> WqkvT rows 0..2047
    k_tr_cvt_f32<<<dim3(4, 64, 16), tb, 0, stream>>>(qk, WqkvT, 2048, 128,
                                                     (long)2048 * 128, (long)128 * 2048);
    // kv_kernel [2][8][2048][128] -> WqkvT rows 2048..4095 (8 K slabs, then 8 V slabs)
    k_tr_cvt_f32<<<dim3(4, 64, 16), tb, 0, stream>>>(kvk, WqkvT + (long)2048 * 2048, 2048, 128,
                                                     (long)2048 * 128, (long)128 * 2048);
    // out_kernel [2048 nh][2048 d] -> WoT [d][nh]
    k_tr_cvt_f32<<<dim3(64, 64, 1), tb, 0, stream>>>(ok, WoT, 2048, 2048, 0, 0);
    k_rope_table<<<T * 64 / 256, 256, 0, stream>>>(rt);
    k_gemm_bt<true><<<32 * 32, 256, 0, stream>>>(xb, WqkvT, Cqkv, T, NCOLS, D);
    k_normrope<<<24 * T / 4, 256, 0, stream>>>(Cqkv, qs, ks, rt, qro, kswp);
    k_tr_v<<<dim3(128, 4, 8), tb, 0, stream>>>(Cqkv, vt);
    k_attn<<<NQ * (T / 64), 256, 0, stream>>>(qro, kswp, vt, enc);
    k_gemm_bt<false><<<32 * 16, 256, 0, stream>>>(enc, WoT, d_out, T, D, D);
}

// Round 9
// 341.038 us; speedup vs baseline: 1.1673x; 1.1673x over previous
//
#include <hip/hip_runtime.h>
#include <hip/hip_bf16.h>

// ---------------------------------------------------------------------------
// Gemma-style attention block, MI355X (gfx950).
// B=1, T=4096, D=2048, N=16 q-heads, KH=8 kv-heads (GQA G=2), H=128,
// sliding window 1024, causal, RMSNorm(q,k) + RoPE, attn scale folded into q.
//
// R8: k_attn rewritten — static softmax (no online max: |S| <= 11.32 by
// Cauchy-Schwarz after RMSNorm, exp(S) safe in bf16/fp32), deferred
// denominator reduce, boundary-only masking, 8 waves x 128 q-rows per block.
// ---------------------------------------------------------------------------

#define DEVINL __device__ __forceinline__

typedef __attribute__((ext_vector_type(4))) float f32x4;
typedef __attribute__((ext_vector_type(8))) short s16x8;
typedef __attribute__((ext_vector_type(4))) unsigned int u32x4;

constexpr int T = 4096, D = 2048, NQ = 16, KH = 8, H = 128;
constexpr int NCOLS = 4096;              // q(2048) | k(1024) | v(1024)
constexpr float EPS = 1e-6f;
constexpr float ATTN_SCALE = 0.08838834764831845f;
constexpr int WINDOW = 1024;

DEVINL unsigned short f2bf(float f) {
    union { float f; unsigned int u; } v; v.f = f;
    unsigned int u = v.u;
    return (unsigned short)((u + 0x7fffu + ((u >> 16) & 1u)) >> 16);
}
DEVINL float bf2f(unsigned short h) {
    union { unsigned int u; float f; } v; v.u = ((unsigned int)h) << 16;
    return v.f;
}
DEVINL void gload_lds16(const unsigned short* g, unsigned short* l) {
    __builtin_amdgcn_global_load_lds(
        (const __attribute__((address_space(1))) unsigned int*)g,
        (__attribute__((address_space(3))) unsigned int*)l, 16, 0, 0);
}

// ---------------------------------------------------------------- convert x
__global__ __launch_bounds__(256) void k_cvt_x(const float* __restrict__ x,
                                               unsigned short* __restrict__ xb, int n8) {
    int i = blockIdx.x * 256 + threadIdx.x;
    if (i >= n8) return;
    const float4* src = (const float4*)x + (long)i * 2;
    float4 a = src[0], b = src[1];
    s16x8 o;
    o[0] = (short)f2bf(a.x); o[1] = (short)f2bf(a.y);
    o[2] = (short)f2bf(a.z); o[3] = (short)f2bf(a.w);
    o[4] = (short)f2bf(b.x); o[5] = (short)f2bf(b.y);
    o[6] = (short)f2bf(b.z); o[7] = (short)f2bf(b.w);
    ((s16x8*)xb)[i] = o;
}

// ---------------------------------------------- transpose+convert f32 slabs
// src [R][C] fp32 per slab -> dst [C][R] bf16 per slab
__global__ __launch_bounds__(256) void k_tr_cvt_f32(const float* __restrict__ src,
                                                    unsigned short* __restrict__ dst,
                                                    int R, int C, long srcSlab, long dstSlab) {
    __shared__ float tile[32][33];
    int slab = blockIdx.z;
    src += (long)slab * srcSlab; dst += (long)slab * dstSlab;
    int c0 = blockIdx.x * 32, r0 = blockIdx.y * 32;
    int tx = threadIdx.x, ty = threadIdx.y;     // (32, 8)
    #pragma unroll
    for (int i = 0; i < 32; i += 8)
        tile[ty + i][tx] = src[(long)(r0 + ty + i) * C + c0 + tx];
    __syncthreads();
    #pragma unroll
    for (int i = 0; i < 32; i += 8)
        dst[(long)(c0 + ty + i) * R + r0 + tx] = f2bf(tile[tx][ty + i]);
}

// ------------------------------------------------------------- rope table
__global__ __launch_bounds__(256) void k_rope_table(float2* __restrict__ rt) {
    int idx = blockIdx.x * 256 + threadIdx.x;     // t*64 + j
    int t = idx >> 6, j = idx & 63;
    float inv = expf(-(float)j * (logf(10000.0f) / 64.0f));   // 10000^(-j/64)
    float a = (float)t * inv;
    float s, c;
    sincosf(a, &s, &c);
    rt[idx] = make_float2(c, s);
}

// ---------------------------------------------------------------- bf16 GEMM
// C[M][N] = A[M][K] * Bt[N][K]^T, 128x128 tile, BK=64, 4 waves, XOR-swizzled
// LDS via pre-swizzled per-lane global source, global_load_lds width 16.
template <bool BF16OUT>
__global__ __launch_bounds__(256) void k_gemm_bt(const unsigned short* __restrict__ A,
                                                 const unsigned short* __restrict__ Bt,
                                                 void* __restrict__ Cout,
                                                 int M, int N, int K) {
    constexpr int BK = 64;
    __shared__ __align__(16) unsigned short As[128 * BK];
    __shared__ __align__(16) unsigned short Bs[128 * BK];

    int nwg = gridDim.x, bid = blockIdx.x;
    int cpx = nwg >> 3;
    int wg = (bid & 7) * cpx + (bid >> 3);        // XCD swizzle (nwg % 8 == 0)
    int nbn = N >> 7;
    int bm = wg / nbn, bn = wg % nbn;

    int tid = threadIdx.x;
    int w = tid >> 6, l = tid & 63;
    int g = l >> 4, lr = l & 15;
    int wrow = (w >> 1) * 64, wcol = (w & 1) * 64;

    const unsigned short* Abase = A + (long)(bm * 128) * K;
    const unsigned short* Bbase = Bt + (long)(bn * 128) * K;

    f32x4 acc[4][4] = {};

    for (int k0 = 0; k0 < K; k0 += BK) {
        #pragma unroll
        for (int j = 0; j < 4; ++j) {
            int chunk = j * 256 + tid;
            int row = chunk >> 3, slot = chunk & 7;
            int sl = slot ^ (row & 7);            // pre-swizzle the source
            gload_lds16(Abase + (long)row * K + k0 + sl * 8,
                        As + (j * 256 + w * 64) * 8);
        }
        #pragma unroll
        for (int j = 0; j < 4; ++j) {
            int chunk = j * 256 + tid;
            int row = chunk >> 3, slot = chunk & 7;
            int sl = slot ^ (row & 7);
            gload_lds16(Bbase + (long)row * K + k0 + sl * 8,
                        Bs + (j * 256 + w * 64) * 8);
        }
        __syncthreads();
        #pragma unroll
        for (int kk = 0; kk < 2; ++kk) {
            s16x8 af[4], bf[4];
            #pragma unroll
            for (int mi = 0; mi < 4; ++mi) {
                int row = wrow + mi * 16 + lr;
                int slot = (kk * 4 + g) ^ (row & 7);
                af[mi] = *(const s16x8*)(As + row * BK + slot * 8);
            }
            #pragma unroll
            for (int ni = 0; ni < 4; ++ni) {
                int row = wcol + ni * 16 + lr;
                int slot = (kk * 4 + g) ^ (row & 7);
                bf[ni] = *(const s16x8*)(Bs + row * BK + slot * 8);
            }
            #pragma unroll
            for (int mi = 0; mi < 4; ++mi)
                #pragma unroll
                for (int ni = 0; ni < 4; ++ni)
                    acc[mi][ni] = __builtin_amdgcn_mfma_f32_16x16x32_bf16(
                        af[mi], bf[ni], acc[mi][ni], 0, 0, 0);
        }
        __syncthreads();
    }

    int crow0 = bm * 128 + wrow + g * 4;
    int ccol0 = bn * 128 + wcol + lr;
    #pragma unroll
    for (int mi = 0; mi < 4; ++mi)
        #pragma unroll
        for (int ni = 0; ni < 4; ++ni)
            #pragma unroll
            for (int j = 0; j < 4; ++j) {
                long r = crow0 + mi * 16 + j;
                long c = ccol0 + ni * 16;
                if (BF16OUT)
                    ((unsigned short*)Cout)[r * N + c] = f2bf(acc[mi][ni][j]);
                else
                    ((float*)Cout)[r * N + c] = acc[mi][ni][j];
            }
}

// --------------------------------------------------------- RMSNorm + RoPE
// One wave per (head, t) row: lane l handles (h=l, h=l+64) rope pair.
__global__ __launch_bounds__(256) void k_normrope(const unsigned short* __restrict__ Cqkv,
                                                  const float* __restrict__ qscale,
                                                  const float* __restrict__ kscale,
                                                  const float2* __restrict__ rt,
                                                  unsigned short* __restrict__ qro,
                                                  unsigned short* __restrict__ ksw) {
    int w = threadIdx.x >> 6, l = threadIdx.x & 63;
    int rid = blockIdx.x * 4 + w;                 // [0, 24*4096)
    int head = rid >> 12;                         // 0..23 (16 q + 8 k)
    int t = rid & 4095;
    int col0 = (head < NQ) ? head * H : D + (head - NQ) * H;
    const unsigned short* row = Cqkv + (long)t * NCOLS + col0;
    float x1 = bf2f(row[l]), x2 = bf2f(row[l + 64]);
    float ss = x1 * x1 + x2 * x2;
    #pragma unroll
    for (int off = 1; off < 64; off <<= 1) ss += __shfl_xor(ss, off);
    float r = rsqrtf(ss * (1.0f / 128.0f) + EPS);
    const float* scale = (head < NQ) ? qscale : kscale;
    float y1 = x1 * r * scale[l], y2 = x2 * r * scale[l + 64];
    float2 cs = rt[t * 64 + l];
    float o1 = y1 * cs.x - y2 * cs.y;
    float o2 = y2 * cs.x + y1 * cs.y;
    if (head < NQ) {
        o1 *= ATTN_SCALE; o2 *= ATTN_SCALE;
        unsigned short* dst = qro + ((long)head * T + t) * H;
        dst[l] = f2bf(o1); dst[l + 64] = f2bf(o2);
    } else {
        unsigned short* dst = ksw + ((long)(head - NQ) * T + t) * H;
        int sx = (t & 7) << 3;                    // 16B-chunk XOR pre-swizzle
        dst[l ^ sx] = f2bf(o1); dst[(l + 64) ^ sx] = f2bf(o2);
    }
}

// --------------------------------------------------- transpose V -> [kh][h][s]
__global__ __launch_bounds__(256) void k_tr_v(const unsigned short* __restrict__ Cqkv,
                                              unsigned short* __restrict__ vt) {
    __shared__ unsigned short tile[32][33];
    int kh = blockIdx.z;
    int h0 = blockIdx.y * 32;
    int s0 = blockIdx.x * 32;
    int tx = threadIdx.x, ty = threadIdx.y;
    #pragma unroll
    for (int i = 0; i < 32; i += 8)
        tile[ty + i][tx] = Cqkv[(long)(s0 + ty + i) * NCOLS + 3072 + kh * H + h0 + tx];
    __syncthreads();
    #pragma unroll
    for (int i = 0; i < 32; i += 8)
        vt[((long)kh * H + h0 + ty + i) * T + s0 + tx] = tile[tx][ty + i];
}

// ------------------------------------------------------------- attention
// Block: 8 waves x 16 q-rows (128 q-rows), one head. KV tile = 64 keys.
// Static softmax: P = exp(S) directly (|S| <= 11.32 guaranteed by RMSNorm +
// Cauchy-Schwarz); denominator accumulated per-lane, reduced once at the end.
__global__ __launch_bounds__(512) void k_attn(const unsigned short* __restrict__ qro,
                                              const unsigned short* __restrict__ ksw,
                                              const unsigned short* __restrict__ vt,
                                              unsigned short* __restrict__ enc) {
    __shared__ __align__(16) unsigned short Ks[64 * 128];      // XOR-swizzled chunks
    __shared__ __align__(16) unsigned short Vs[128 * 72];      // [h][s], padded rows
    __shared__ __align__(16) unsigned short Ps[8][16 * 72];    // per-wave P

    int nwg = gridDim.x, bid = blockIdx.x;
    int cpx = nwg >> 3;
    int wg = (bid & 7) * cpx + (bid >> 3);        // XCD swizzle (512 % 8 == 0)
    int n = wg >> 5;                 // head (16 heads x 32 q-blocks)
    int qblk = wg & 31;
    int kvh = n >> 1;                // GQA: kv head = n // 2
    int q0 = qblk * 128;

    int tid = threadIdx.x, w = tid >> 6, l = tid & 63;
    int g = l >> 4, lr = l & 15;
    int qw0 = q0 + w * 16;           // this wave's first q-row

    const unsigned short* Kb = ksw + (long)kvh * T * H;
    const unsigned short* Vb = vt + (long)kvh * H * T;

    // Q fragments (A-operand), attn-scale already folded in
    s16x8 qf[4];
    const unsigned short* qrow = qro + ((long)n * T + qw0 + lr) * H;
    #pragma unroll
    for (int c = 0; c < 4; ++c)
        qf[c] = *(const s16x8*)(qrow + c * 32 + g * 8);

    float psum[4] = {};              // per-lane partial softmax denominators
    f32x4 acc[8] = {};

    int ts_lo = q0 - (WINDOW - 1);
    ts_lo = ts_lo < 0 ? 0 : (ts_lo & ~63);
    int ts_hi = q0 + 64;             // covers causal tiles for rows up to q0+127

    for (int ts = ts_lo; ts <= ts_hi; ts += 64) {
        // stage K tile (linear dest; source pre-swizzled): 2 chunks/thread
        #pragma unroll
        for (int j = 0; j < 2; ++j)
            gload_lds16(Kb + (long)ts * H + (j * 512 + tid) * 8,
                        Ks + (j * 512 + w * 64) * 8);
        // stage V tile (reg-staged into padded LDS rows): 2 chunks/thread
        u32x4 vreg[2];
        #pragma unroll
        for (int j = 0; j < 2; ++j) {
            int chunk = j * 512 + tid;
            int h = chunk >> 3, slot = chunk & 7;
            vreg[j] = *(const u32x4*)(Vb + (long)h * T + ts + slot * 8);
        }
        #pragma unroll
        for (int j = 0; j < 2; ++j) {
            int chunk = j * 512 + tid;
            int h = chunk >> 3, slot = chunk & 7;
            *(u32x4*)(Vs + h * 72 + slot * 8) = vreg[j];
        }
        __syncthreads();

        // wave-active: tile overlaps [qw0-1023, qw0+15]
        if (ts <= qw0 + 15 && ts + 63 >= qw0 - (WINDOW - 1)) {
            // S = Q K^T : 4 s-subtiles of 16
            f32x4 sf[4];
            #pragma unroll
            for (int sh = 0; sh < 4; ++sh) {
                f32x4 s4 = {};
                int srow = sh * 16 + lr;
                int sx = srow & 7;
                #pragma unroll
                for (int c = 0; c < 4; ++c) {
                    int slot = (c * 4 + g) ^ sx;
                    s16x8 kf = *(const s16x8*)(Ks + srow * 128 + slot * 8);
                    s4 = __builtin_amdgcn_mfma_f32_16x16x32_bf16(qf[c], kf, s4, 0, 0, 0);
                }
                sf[sh] = s4;
            }
            // boundary tiles only: causal or window clipping possible
            bool needmask = (ts + 63 > qw0) || (ts < qw0 - (WINDOW - 16));
            if (needmask) {
                #pragma unroll
                for (int j = 0; j < 4; ++j) {
                    int q = qw0 + g * 4 + j;
                    #pragma unroll
                    for (int sh = 0; sh < 4; ++sh) {
                        int s = ts + sh * 16 + lr;
                        bool valid = (s <= q) && (q - s < WINDOW);
                        sf[sh][j] = valid ? sf[sh][j] : -1e30f;   // exp -> 0
                    }
                }
            }
            // static softmax: P = exp(S); accumulate per-lane denominator
            unsigned short* P = &Ps[w][0];
            #pragma unroll
            for (int j = 0; j < 4; ++j) {
                int prow = g * 4 + j;
                #pragma unroll
                for (int sh = 0; sh < 4; ++sh) {
                    float p = __expf(sf[sh][j]);
                    psum[j] += p;
                    P[prow * 72 + sh * 16 + lr] = f2bf(p);
                }
            }
            // PV: acc[q][h] += P[q][s] * V[s][h]
            #pragma unroll
            for (int kk = 0; kk < 2; ++kk) {
                s16x8 pf = *(const s16x8*)(P + lr * 72 + kk * 32 + g * 8);
                #pragma unroll
                for (int hc = 0; hc < 8; ++hc) {
                    int h = hc * 16 + lr;
                    s16x8 vf = *(const s16x8*)(Vs + h * 72 + kk * 32 + g * 8);
                    acc[hc] = __builtin_amdgcn_mfma_f32_16x16x32_bf16(pf, vf, acc[hc], 0, 0, 0);
                }
            }
        }
        __syncthreads();
    }

    // epilogue: single cross-lane denominator reduce, normalize, write enc
    #pragma unroll
    for (int j = 0; j < 4; ++j) {
        float ps = psum[j];
        ps += __shfl_xor(ps, 1);
        ps += __shfl_xor(ps, 2);
        ps += __shfl_xor(ps, 4);
        ps += __shfl_xor(ps, 8);
        float inv = 1.0f / ps;
        long r = qw0 + g * 4 + j;
        unsigned short* dst = enc + r * (long)D + n * H;
        #pragma unroll
        for (int hc = 0; hc < 8; ++hc)
            dst[hc * 16 + lr] = f2bf(acc[hc][j] * inv);
    }
}

// ---------------------------------------------------------------------------
extern "C" void kernel_launch(void* const* d_in, const int* in_sizes, int n_in,
                              void* d_out, int out_size, void* d_ws, size_t ws_size,
                              hipStream_t stream) {
    const float* x   = (const float*)d_in[0];
    const float* qk  = (const float*)d_in[1];
    const float* kvk = (const float*)d_in[2];
    const float* ok  = (const float*)d_in[3];
    const float* qs  = (const float*)d_in[4];
    const float* ks  = (const float*)d_in[5];

    char* ws = (char*)d_ws;
    unsigned short* xb    = (unsigned short*)(ws);                 // 16 MB
    unsigned short* WqkvT = (unsigned short*)(ws + 16777216);      // 16 MB
    unsigned short* WoT   = (unsigned short*)(ws + 33554432);      //  8 MB
    unsigned short* Cqkv  = (unsigned short*)(ws + 41943040);      // 32 MB
    unsigned short* qro   = (unsigned short*)(ws + 75497472);      // 16 MB
    unsigned short* kswp  = (unsigned short*)(ws + 92274688);      //  8 MB
    unsigned short* vt    = (unsigned short*)(ws + 100663296);     //  8 MB
    unsigned short* enc   = (unsigned short*)(ws + 109051904);     // 16 MB
    float2*         rt    = (float2*)(ws + 125829120);             //  2 MB

    dim3 tb(32, 8);
    k_cvt_x<<<4096, 256, 0, stream>>>(x, xb, T * D / 8);
    // q_kernel [16][2048][128] -> WqkvT rows 0..2047
    k_tr_cvt_f32<<<dim3(4, 64, 16), tb, 0, stream>>>(qk, WqkvT, 2048, 128,
                                                     (long)2048 * 128, (long)128 * 2048);
    // kv_kernel [2][8][2048][128] -> WqkvT rows 2048..4095 (8 K slabs, then 8 V slabs)
    k_tr_cvt_f32<<<dim3(4, 64, 16), tb, 0, stream>>>(kvk, WqkvT + (long)2048 * 2048, 2048, 128,
                                                     (long)2048 * 128, (long)128 * 2048);
    // out_kernel [2048 nh][2048 d] -> WoT [d][nh]
    k_tr_cvt_f32<<<dim3(64, 64, 1), tb, 0, stream>>>(ok, WoT, 2048, 2048, 0, 0);
    k_rope_table<<<T * 64 / 256, 256, 0, stream>>>(rt);
    k_gemm_bt<true><<<32 * 32, 256, 0, stream>>>(xb, WqkvT, Cqkv, T, NCOLS, D);
    k_normrope<<<24 * T / 4, 256, 0, stream>>>(Cqkv, qs, ks, rt, qro, kswp);
    k_tr_v<<<dim3(128, 4, 8), tb, 0, stream>>>(Cqkv, vt);
    k_attn<<<NQ * (T / 128), 512, 0, stream>>>(qro, kswp, vt, enc);
    k_gemm_bt<false><<<32 * 16, 256, 0, stream>>>(enc, WoT, d_out, T, D, D);
}

// Round 10
// 328.358 us; speedup vs baseline: 1.2123x; 1.0386x over previous
//
#include <hip/hip_runtime.h>
#include <hip/hip_bf16.h>

// ---------------------------------------------------------------------------
// Gemma-style attention block, MI355X (gfx950).
// B=1, T=4096, D=2048, N=16 q-heads, KH=8 kv-heads (GQA G=2), H=128,
// sliding window 1024, causal, RMSNorm(q,k) + RoPE, attn scale folded into q.
//
// R10: GEMMs ported to 8-phase counted-vmcnt schedule (T3+T4+T5):
//  - 256x256 (QKV) / 256x128 (out-proj) tiles, BK=64 as 2 k-halves, 8 waves.
//  - 4 LDS slots/operand (ring, 2 K-tiles deep), 1 half-tile prefetch/phase.
//  - raw s_barrier + s_waitcnt vmcnt(CHB+2); NEVER vmcnt(0) in the main loop
//    (no __syncthreads in the GEMM - it would drain the pipeline).
//  - per-phase MFMA cluster wrapped in s_setprio(1)/(0).
//  Tail phases prefetch past K (<=0.8MB overread, stays inside d_ws, unread).
// R8: k_attn static softmax (|S|<=11.32 post-RMSNorm), deferred denominator.
// ---------------------------------------------------------------------------

#define DEVINL __device__ __forceinline__

typedef __attribute__((ext_vector_type(4))) float f32x4;
typedef __attribute__((ext_vector_type(8))) short s16x8;
typedef __attribute__((ext_vector_type(4))) unsigned int u32x4;

constexpr int T = 4096, D = 2048, NQ = 16, KH = 8, H = 128;
constexpr int NCOLS = 4096;              // q(2048) | k(1024) | v(1024)
constexpr float EPS = 1e-6f;
constexpr float ATTN_SCALE = 0.08838834764831845f;
constexpr int WINDOW = 1024;

DEVINL unsigned short f2bf(float f) {
    union { float f; unsigned int u; } v; v.f = f;
    unsigned int u = v.u;
    return (unsigned short)((u + 0x7fffu + ((u >> 16) & 1u)) >> 16);
}
DEVINL float bf2f(unsigned short h) {
    union { unsigned int u; float f; } v; v.u = ((unsigned int)h) << 16;
    return v.f;
}
DEVINL void gload_lds16(const unsigned short* g, unsigned short* l) {
    __builtin_amdgcn_global_load_lds(
        (const __attribute__((address_space(1))) unsigned int*)g,
        (__attribute__((address_space(3))) unsigned int*)l, 16, 0, 0);
}

// ---------------------------------------------------------------- convert x
__global__ __launch_bounds__(256) void k_cvt_x(const float* __restrict__ x,
                                               unsigned short* __restrict__ xb, int n8) {
    int i = blockIdx.x * 256 + threadIdx.x;
    if (i >= n8) return;
    const float4* src = (const float4*)x + (long)i * 2;
    float4 a = src[0], b = src[1];
    s16x8 o;
    o[0] = (short)f2bf(a.x); o[1] = (short)f2bf(a.y);
    o[2] = (short)f2bf(a.z); o[3] = (short)f2bf(a.w);
    o[4] = (short)f2bf(b.x); o[5] = (short)f2bf(b.y);
    o[6] = (short)f2bf(b.z); o[7] = (short)f2bf(b.w);
    ((s16x8*)xb)[i] = o;
}

// ---------------------------------------------- transpose+convert f32 slabs
__global__ __launch_bounds__(256) void k_tr_cvt_f32(const float* __restrict__ src,
                                                    unsigned short* __restrict__ dst,
                                                    int R, int C, long srcSlab, long dstSlab) {
    __shared__ float tile[32][33];
    int slab = blockIdx.z;
    src += (long)slab * srcSlab; dst += (long)slab * dstSlab;
    int c0 = blockIdx.x * 32, r0 = blockIdx.y * 32;
    int tx = threadIdx.x, ty = threadIdx.y;     // (32, 8)
    #pragma unroll
    for (int i = 0; i < 32; i += 8)
        tile[ty + i][tx] = src[(long)(r0 + ty + i) * C + c0 + tx];
    __syncthreads();
    #pragma unroll
    for (int i = 0; i < 32; i += 8)
        dst[(long)(c0 + ty + i) * R + r0 + tx] = f2bf(tile[tx][ty + i]);
}

// ------------------------------------------------------------- rope table
__global__ __launch_bounds__(256) void k_rope_table(float2* __restrict__ rt) {
    int idx = blockIdx.x * 256 + threadIdx.x;     // t*64 + j
    int t = idx >> 6, j = idx & 63;
    float inv = expf(-(float)j * (logf(10000.0f) / 64.0f));   // 10000^(-j/64)
    float a = (float)t * inv;
    float s, c;
    sincosf(a, &s, &c);
    rt[idx] = make_float2(c, s);
}

// --------------------------------------------------- 8-phase MFMA GEMM
// C[M][N] = A[M][K] * Bt[N][K]^T. Tile BM=256 x BN, BK=64 (2 k-halves of 32).
// 8 waves (2M x 4N), 512 threads. LDS: 4 slots/operand of [rows][32] bf16,
// chunk-XOR swizzled (s' = s ^ ((row>>1)&3)) via pre-swizzled global source.
// Phase p of K-tile t: {vmcnt?; s_barrier; ds_reads; 1 half-tile prefetch;
// setprio(1); MFMA x 8*NF; setprio(0)}. vmcnt(CHB+2) at P1/P3/P5/P7 only.
template <bool BF16OUT, int BN>
__global__ __launch_bounds__(512, 2) void k_gemm8(const unsigned short* __restrict__ A,
                                                  const unsigned short* __restrict__ Bt,
                                                  void* __restrict__ Cout,
                                                  int M, int N, int K) {
    constexpr int WN  = BN / 4;           // per-wave N extent (64 / 32)
    constexpr int NR  = WN / 16;          // n-frags per wave (4 / 2)
    constexpr int NF  = NR / 2;           // n-frags per phase (2 / 1)
    constexpr int CHB = (BN * 4) / 512;   // B gload_lds per half-tile (2 / 1)
    constexpr int VMC = CHB + 2;          // counted wait: newest 2 phases stay in flight
    constexpr int ASL = 256 * 32;         // A slot size (ushorts)
    constexpr int BSL = BN * 32;
    __shared__ __align__(16) unsigned short As[4 * ASL];
    __shared__ __align__(16) unsigned short Bs[4 * BSL];

    int nwg = gridDim.x, bid = blockIdx.x;
    int cpx = nwg >> 3;
    int wg = (bid & 7) * cpx + (bid >> 3);     // XCD swizzle (nwg % 8 == 0)
    int nbn = N / BN;
    int bm = wg / nbn, bn = wg % nbn;

    int tid = threadIdx.x;
    int w = tid >> 6, l = tid & 63;
    int g = l >> 4, lr = l & 15;
    int wm = w >> 2, wn = w & 3;

    const unsigned short* Ab = A + (long)(bm * 256) * K;
    const unsigned short* Bb = Bt + (long)(bn * BN) * K;

    f32x4 acc[8][NR] = {};
    s16x8 a[8], b[NF];

    auto stA = [&](int slot, int tt, int h) {
        #pragma unroll
        for (int j = 0; j < 2; ++j) {
            int c = j * 512 + tid;
            int row = c >> 2, sp = c & 3;
            int s = sp ^ ((row >> 1) & 3);     // pre-swizzle the source
            gload_lds16(Ab + (long)row * K + tt * 64 + h * 32 + s * 8,
                        As + slot * ASL + (j * 512 + w * 64) * 8);
        }
    };
    auto stB = [&](int slot, int tt, int h) {
        #pragma unroll
        for (int j = 0; j < CHB; ++j) {
            int c = j * 512 + tid;
            int row = c >> 2, sp = c & 3;
            int s = sp ^ ((row >> 1) & 3);
            gload_lds16(Bb + (long)row * K + tt * 64 + h * 32 + s * 8,
                        Bs + slot * BSL + (j * 512 + w * 64) * 8);
        }
    };
    auto rdA = [&](int slot) {
        #pragma unroll
        for (int mi = 0; mi < 8; ++mi) {
            int row = wm * 128 + mi * 16 + lr;
            int sp = g ^ ((row >> 1) & 3);
            a[mi] = *(const s16x8*)(As + slot * ASL + row * 32 + sp * 8);
        }
    };
    auto rdB = [&](int slot, int nh) {
        #pragma unroll
        for (int f = 0; f < NF; ++f) {
            int row = wn * WN + (nh * NF + f) * 16 + lr;
            int sp = g ^ ((row >> 1) & 3);
            b[f] = *(const s16x8*)(Bs + slot * BSL + row * 32 + sp * 8);
        }
    };
    auto mm = [&](int nh) {
        __builtin_amdgcn_s_setprio(1);
        #pragma unroll
        for (int mi = 0; mi < 8; ++mi)
            #pragma unroll
            for (int f = 0; f < NF; ++f)
                acc[mi][nh * NF + f] = __builtin_amdgcn_mfma_f32_16x16x32_bf16(
                    a[mi], b[f], acc[mi][nh * NF + f], 0, 0, 0);
        __builtin_amdgcn_s_setprio(0);
    };
#define GVM()  asm volatile("s_waitcnt vmcnt(%0)" :: "i"(VMC) : "memory")
#define GBAR() { __builtin_amdgcn_s_barrier(); asm volatile("" ::: "memory"); }

    // prologue: tile0 all 4 half-tiles + tile1 {Ah0, Bh0, Ah1} (ages match loop)
    stA(0, 0, 0); stB(0, 0, 0); stA(1, 0, 1); stB(1, 0, 1);
    stA(2, 1, 0); stB(2, 1, 0); stA(3, 1, 1);

    int KT = K >> 6;
    for (int u = 0; u < (KT >> 1); ++u) {
        int te = 2 * u, to = te + 1;
        // P1 (te, k0, n-half0)
        GVM(); GBAR();
        rdA(0); rdB(0, 0); stB(3, to, 1);      mm(0);
        // P2 (te, k0, n-half1)
        GBAR();
        rdB(0, 1);         stA(0, te + 2, 0);  mm(1);
        // P3 (te, k1, n-half0)
        GVM(); GBAR();
        rdA(1); rdB(1, 0); stB(0, te + 2, 0);  mm(0);
        // P4 (te, k1, n-half1)
        GBAR();
        rdB(1, 1);         stA(1, te + 2, 1);  mm(1);
        // P5 (to, k0, n-half0)
        GVM(); GBAR();
        rdA(2); rdB(2, 0); stB(1, te + 2, 1);  mm(0);
        // P6 (to, k0, n-half1)
        GBAR();
        rdB(2, 1);         stA(2, to + 2, 0);  mm(1);
        // P7 (to, k1, n-half0)
        GVM(); GBAR();
        rdA(3); rdB(3, 0); stB(2, to + 2, 0);  mm(0);
        // P8 (to, k1, n-half1)
        GBAR();
        rdB(3, 1);         stA(3, to + 2, 1);  mm(1);
    }
#undef GVM
#undef GBAR

    int crow0 = bm * 256 + wm * 128 + g * 4;
    int ccol0 = bn * BN + wn * WN + lr;
    #pragma unroll
    for (int mi = 0; mi < 8; ++mi)
        #pragma unroll
        for (int ni = 0; ni < NR; ++ni)
            #pragma unroll
            for (int j = 0; j < 4; ++j) {
                long r = crow0 + mi * 16 + j;
                long c = ccol0 + ni * 16;
                if (BF16OUT)
                    ((unsigned short*)Cout)[r * N + c] = f2bf(acc[mi][ni][j]);
                else
                    ((float*)Cout)[r * N + c] = acc[mi][ni][j];
            }
}

// --------------------------------------------------------- RMSNorm + RoPE
__global__ __launch_bounds__(256) void k_normrope(const unsigned short* __restrict__ Cqkv,
                                                  const float* __restrict__ qscale,
                                                  const float* __restrict__ kscale,
                                                  const float2* __restrict__ rt,
                                                  unsigned short* __restrict__ qro,
                                                  unsigned short* __restrict__ ksw) {
    int w = threadIdx.x >> 6, l = threadIdx.x & 63;
    int rid = blockIdx.x * 4 + w;                 // [0, 24*4096)
    int head = rid >> 12;                         // 0..23 (16 q + 8 k)
    int t = rid & 4095;
    int col0 = (head < NQ) ? head * H : D + (head - NQ) * H;
    const unsigned short* row = Cqkv + (long)t * NCOLS + col0;
    float x1 = bf2f(row[l]), x2 = bf2f(row[l + 64]);
    float ss = x1 * x1 + x2 * x2;
    #pragma unroll
    for (int off = 1; off < 64; off <<= 1) ss += __shfl_xor(ss, off);
    float r = rsqrtf(ss * (1.0f / 128.0f) + EPS);
    const float* scale = (head < NQ) ? qscale : kscale;
    float y1 = x1 * r * scale[l], y2 = x2 * r * scale[l + 64];
    float2 cs = rt[t * 64 + l];
    float o1 = y1 * cs.x - y2 * cs.y;
    float o2 = y2 * cs.x + y1 * cs.y;
    if (head < NQ) {
        o1 *= ATTN_SCALE; o2 *= ATTN_SCALE;
        unsigned short* dst = qro + ((long)head * T + t) * H;
        dst[l] = f2bf(o1); dst[l + 64] = f2bf(o2);
    } else {
        unsigned short* dst = ksw + ((long)(head - NQ) * T + t) * H;
        int sx = (t & 7) << 3;                    // 16B-chunk XOR pre-swizzle
        dst[l ^ sx] = f2bf(o1); dst[(l + 64) ^ sx] = f2bf(o2);
    }
}

// --------------------------------------------------- transpose V -> [kh][h][s]
__global__ __launch_bounds__(256) void k_tr_v(const unsigned short* __restrict__ Cqkv,
                                              unsigned short* __restrict__ vt) {
    __shared__ unsigned short tile[32][33];
    int kh = blockIdx.z;
    int h0 = blockIdx.y * 32;
    int s0 = blockIdx.x * 32;
    int tx = threadIdx.x, ty = threadIdx.y;
    #pragma unroll
    for (int i = 0; i < 32; i += 8)
        tile[ty + i][tx] = Cqkv[(long)(s0 + ty + i) * NCOLS + 3072 + kh * H + h0 + tx];
    __syncthreads();
    #pragma unroll
    for (int i = 0; i < 32; i += 8)
        vt[((long)kh * H + h0 + ty + i) * T + s0 + tx] = tile[tx][ty + i];
}

// ------------------------------------------------------------- attention
// Block: 8 waves x 16 q-rows (128 q-rows), one head. KV tile = 64 keys.
// Static softmax: P = exp(S) directly; per-lane denominator, one final reduce.
__global__ __launch_bounds__(512) void k_attn(const unsigned short* __restrict__ qro,
                                              const unsigned short* __restrict__ ksw,
                                              const unsigned short* __restrict__ vt,
                                              unsigned short* __restrict__ enc) {
    __shared__ __align__(16) unsigned short Ks[64 * 128];      // XOR-swizzled chunks
    __shared__ __align__(16) unsigned short Vs[128 * 72];      // [h][s], padded rows
    __shared__ __align__(16) unsigned short Ps[8][16 * 72];    // per-wave P

    int nwg = gridDim.x, bid = blockIdx.x;
    int cpx = nwg >> 3;
    int wg = (bid & 7) * cpx + (bid >> 3);        // XCD swizzle (512 % 8 == 0)
    int n = wg >> 5;                 // head (16 heads x 32 q-blocks)
    int qblk = wg & 31;
    int kvh = n >> 1;                // GQA: kv head = n // 2
    int q0 = qblk * 128;

    int tid = threadIdx.x, w = tid >> 6, l = tid & 63;
    int g = l >> 4, lr = l & 15;
    int qw0 = q0 + w * 16;           // this wave's first q-row

    const unsigned short* Kb = ksw + (long)kvh * T * H;
    const unsigned short* Vb = vt + (long)kvh * H * T;

    s16x8 qf[4];
    const unsigned short* qrow = qro + ((long)n * T + qw0 + lr) * H;
    #pragma unroll
    for (int c = 0; c < 4; ++c)
        qf[c] = *(const s16x8*)(qrow + c * 32 + g * 8);

    float psum[4] = {};
    f32x4 acc[8] = {};

    int ts_lo = q0 - (WINDOW - 1);
    ts_lo = ts_lo < 0 ? 0 : (ts_lo & ~63);
    int ts_hi = q0 + 64;

    for (int ts = ts_lo; ts <= ts_hi; ts += 64) {
        #pragma unroll
        for (int j = 0; j < 2; ++j)
            gload_lds16(Kb + (long)ts * H + (j * 512 + tid) * 8,
                        Ks + (j * 512 + w * 64) * 8);
        u32x4 vreg[2];
        #pragma unroll
        for (int j = 0; j < 2; ++j) {
            int chunk = j * 512 + tid;
            int h = chunk >> 3, slot = chunk & 7;
            vreg[j] = *(const u32x4*)(Vb + (long)h * T + ts + slot * 8);
        }
        #pragma unroll
        for (int j = 0; j < 2; ++j) {
            int chunk = j * 512 + tid;
            int h = chunk >> 3, slot = chunk & 7;
            *(u32x4*)(Vs + h * 72 + slot * 8) = vreg[j];
        }
        __syncthreads();

        if (ts <= qw0 + 15 && ts + 63 >= qw0 - (WINDOW - 1)) {
            f32x4 sf[4];
            #pragma unroll
            for (int sh = 0; sh < 4; ++sh) {
                f32x4 s4 = {};
                int srow = sh * 16 + lr;
                int sx = srow & 7;
                #pragma unroll
                for (int c = 0; c < 4; ++c) {
                    int slot = (c * 4 + g) ^ sx;
                    s16x8 kf = *(const s16x8*)(Ks + srow * 128 + slot * 8);
                    s4 = __builtin_amdgcn_mfma_f32_16x16x32_bf16(qf[c], kf, s4, 0, 0, 0);
                }
                sf[sh] = s4;
            }
            bool needmask = (ts + 63 > qw0) || (ts < qw0 - (WINDOW - 16));
            if (needmask) {
                #pragma unroll
                for (int j = 0; j < 4; ++j) {
                    int q = qw0 + g * 4 + j;
                    #pragma unroll
                    for (int sh = 0; sh < 4; ++sh) {
                        int s = ts + sh * 16 + lr;
                        bool valid = (s <= q) && (q - s < WINDOW);
                        sf[sh][j] = valid ? sf[sh][j] : -1e30f;   // exp -> 0
                    }
                }
            }
            unsigned short* P = &Ps[w][0];
            #pragma unroll
            for (int j = 0; j < 4; ++j) {
                int prow = g * 4 + j;
                #pragma unroll
                for (int sh = 0; sh < 4; ++sh) {
                    float p = __expf(sf[sh][j]);
                    psum[j] += p;
                    P[prow * 72 + sh * 16 + lr] = f2bf(p);
                }
            }
            #pragma unroll
            for (int kk = 0; kk < 2; ++kk) {
                s16x8 pf = *(const s16x8*)(P + lr * 72 + kk * 32 + g * 8);
                #pragma unroll
                for (int hc = 0; hc < 8; ++hc) {
                    int h = hc * 16 + lr;
                    s16x8 vf = *(const s16x8*)(Vs + h * 72 + kk * 32 + g * 8);
                    acc[hc] = __builtin_amdgcn_mfma_f32_16x16x32_bf16(pf, vf, acc[hc], 0, 0, 0);
                }
            }
        }
        __syncthreads();
    }

    #pragma unroll
    for (int j = 0; j < 4; ++j) {
        float ps = psum[j];
        ps += __shfl_xor(ps, 1);
        ps += __shfl_xor(ps, 2);
        ps += __shfl_xor(ps, 4);
        ps += __shfl_xor(ps, 8);
        float inv = 1.0f / ps;
        long r = qw0 + g * 4 + j;
        unsigned short* dst = enc + r * (long)D + n * H;
        #pragma unroll
        for (int hc = 0; hc < 8; ++hc)
            dst[hc * 16 + lr] = f2bf(acc[hc][j] * inv);
    }
}

// ---------------------------------------------------------------------------
extern "C" void kernel_launch(void* const* d_in, const int* in_sizes, int n_in,
                              void* d_out, int out_size, void* d_ws, size_t ws_size,
                              hipStream_t stream) {
    const float* x   = (const float*)d_in[0];
    const float* qk  = (const float*)d_in[1];
    const float* kvk = (const float*)d_in[2];
    const float* ok  = (const float*)d_in[3];
    const float* qs  = (const float*)d_in[4];
    const float* ks  = (const float*)d_in[5];

    char* ws = (char*)d_ws;
    unsigned short* xb    = (unsigned short*)(ws);                 // 16 MB
    unsigned short* WqkvT = (unsigned short*)(ws + 16777216);      // 16 MB
    unsigned short* WoT   = (unsigned short*)(ws + 33554432);      //  8 MB
    unsigned short* Cqkv  = (unsigned short*)(ws + 41943040);      // 32 MB
    unsigned short* qro   = (unsigned short*)(ws + 75497472);      // 16 MB
    unsigned short* kswp  = (unsigned short*)(ws + 92274688);      //  8 MB
    unsigned short* vt    = (unsigned short*)(ws + 100663296);     //  8 MB
    unsigned short* enc   = (unsigned short*)(ws + 109051904);     // 16 MB
    float2*         rt    = (float2*)(ws + 125829120);             //  2 MB

    dim3 tb(32, 8);
    k_cvt_x<<<4096, 256, 0, stream>>>(x, xb, T * D / 8);
    k_tr_cvt_f32<<<dim3(4, 64, 16), tb, 0, stream>>>(qk, WqkvT, 2048, 128,
                                                     (long)2048 * 128, (long)128 * 2048);
    k_tr_cvt_f32<<<dim3(4, 64, 16), tb, 0, stream>>>(kvk, WqkvT + (long)2048 * 2048, 2048, 128,
                                                     (long)2048 * 128, (long)128 * 2048);
    k_tr_cvt_f32<<<dim3(64, 64, 1), tb, 0, stream>>>(ok, WoT, 2048, 2048, 0, 0);
    k_rope_table<<<T * 64 / 256, 256, 0, stream>>>(rt);
    k_gemm8<true, 256><<<256, 512, 0, stream>>>(xb, WqkvT, Cqkv, T, NCOLS, D);
    k_normrope<<<24 * T / 4, 256, 0, stream>>>(Cqkv, qs, ks, rt, qro, kswp);
    k_tr_v<<<dim3(128, 4, 8), tb, 0, stream>>>(Cqkv, vt);
    k_attn<<<NQ * (T / 128), 512, 0, stream>>>(qro, kswp, vt, enc);
    k_gemm8<false, 128><<<256, 512, 0, stream>>>(enc, WoT, d_out, T, D, D);
}